// Round 2
// baseline (448.742 us; speedup 1.0000x reference)
//
#include <hip/hip_runtime.h>
#include <cstdint>

// SpikingCNN: B=8192, D=784, H=128, O=10, T=20, beta=0.9, thr=1.0
// R18 == R17 resubmit (previous bench was an infra failure: container
// acquisition failed twice; no kernel signal).
// R17: occupancy fix for the fused spike_gemm. Counters (R16): VALUBusy 80%,
// MfmaUtil 12%, Occupancy 21%, bank-conflict 0 -> VALU-bound on threefry with
// ~20% issue holes; VGPR=92 (acc[4][4]=64 regs) caps at 5 waves/SIMD and grid
// 1280 = exactly 5 blocks/CU leaves zero slack. Change: 64-row blocks
// (grid 2560), acc[2][4]=32 regs, __launch_bounds__(256,8) -> 64 VGPR,
// 8 blocks/CU resident (LDS 6.4KB), 32 waves/CU. RNG sequence and per-element
// GEMM accumulation order (ko->p->mfma) are bit-identical to R16.
//  - prep stores pre-shifted Ts = ceil(x*2^23)<<9 ; bits>>9 < T <=> bits < Ts
//  - cmp+addc 2-instr bit accumulate (j descending), asm vcc chain.
//  RNG (r9-verified): (x0,x1)=threefry2x32((0,42),(0,n)), n=tb*784+d,
//  bits=x0^x1. GEMM accumulation order / C-layout: r10/r12-verified.
//  prep / lif1 / lif2 byte-identical to R16 (absmax 0.0).

#define T_STEPS 20
#define B_SZ   8192
#define D_SZ   784
#define H_SZ   128
#define O_SZ   10
#define CUR1_BYTES  83886080u                 // 20*8192*128*4
#define MASKS_OFF   83886080u                 // B1 masks: 655360 B
#define WP_OFF      84541440u                 // weight planes: 614400 B
#define THR_OFF     101539840u                // thresholds: 8192*800*4 = 26214400 B

typedef __attribute__((ext_vector_type(8))) short short8;
typedef __attribute__((ext_vector_type(4))) float f32x4;
typedef unsigned short ushort_t;

// rotl via v_alignbit_b32 (r15-verified: 1 instr/round).
#define ROTL_ASM(dst, src, sh)                                        \
  asm("v_alignbit_b32 %0, %1, %1, %2" : "=v"(dst) : "v"(src), "n"(32 - (sh)))

// JAX threefry2x32, key = (0, 42) from jax.random.key(42).
__device__ __forceinline__ void threefry_0_42(uint32_t c0, uint32_t c1,
                                              uint32_t& o0, uint32_t& o1) {
  const uint32_t ks0 = 0u;
  const uint32_t ks1 = 42u;
  const uint32_t ks2 = 0u ^ 42u ^ 0x1BD11BDAu;
  uint32_t x0 = c0 + ks0;
  uint32_t x1 = c1 + ks1;
  uint32_t r;
#define TF_R(rot) { x0 += x1; ROTL_ASM(r, x1, rot); x1 = r ^ x0; }
  TF_R(13) TF_R(15) TF_R(26) TF_R(6)
  x0 += ks1; x1 += ks2 + 1u;
  TF_R(17) TF_R(29) TF_R(16) TF_R(24)
  x0 += ks2; x1 += ks0 + 2u;
  TF_R(13) TF_R(15) TF_R(26) TF_R(6)
  x0 += ks0; x1 += ks1 + 3u;
  TF_R(17) TF_R(29) TF_R(16) TF_R(24)
  x0 += ks1; x1 += ks2 + 4u;
  TF_R(13) TF_R(15) TF_R(26) TF_R(6)
  x0 += ks2; x1 += ks0 + 5u;
#undef TF_R
  o0 = x0; o1 = x1;
}

__device__ __forceinline__ uint32_t rne_bf16_bits(float f) {
  uint32_t u = __float_as_uint(f);
  return (u + 0x7fffu + ((u >> 16) & 1u)) & 0xffff0000u;
}

// ---------------------------------------------------------------------------
// P: prep. Blocks 0..127: split w1 into 3 exact bf16 planes [128][800].
// Blocks 128..3327: pre-shifted thresholds thresh[b][d] = ceil(x*2^23)<<9,
// d in [784,800) padded 0 (never spikes; hits only zero weights).
// ---------------------------------------------------------------------------
__global__ __launch_bounds__(256) void prep(
    const float* __restrict__ w1, const float* __restrict__ x,
    ushort_t* __restrict__ wp, uint32_t* __restrict__ thresh) {
  if (blockIdx.x < 128) {
    const int h = blockIdx.x;
    for (int k = threadIdx.x; k < 800; k += 256) {
      float w = (k < D_SZ) ? w1[h * D_SZ + k] : 0.0f;
      uint32_t hb = rne_bf16_bits(w);
      float hi = __uint_as_float(hb);
      float r1 = w - hi;                      // exact
      uint32_t mb = rne_bf16_bits(r1);
      float mid = __uint_as_float(mb);
      float lo = r1 - mid;                    // exact
      uint32_t lb = __float_as_uint(lo);
      wp[0 * 102400 + h * 800 + k] = (ushort_t)(hb >> 16);
      wp[1 * 102400 + h * 800 + k] = (ushort_t)(mb >> 16);
      wp[2 * 102400 + h * 800 + k] = (ushort_t)(lb >> 16);
    }
  } else {
    const int gid = (blockIdx.x - 128) * 256 + threadIdx.x;  // 0..819199
    const int b = gid / 100;
    const int y = gid - b * 100;
    const int d0 = y << 3;
    uint4 T0 = {0u, 0u, 0u, 0u}, T1 = {0u, 0u, 0u, 0u};
    if (y < 98) {                                  // d0+7 <= 783
      const float* xr = x + (size_t)b * D_SZ + d0;
      float4 v0 = *(const float4*)xr;
      float4 v1 = *(const float4*)(xr + 4);
      T0.x = (uint32_t)__builtin_ceilf(v0.x * 8388608.0f) << 9;
      T0.y = (uint32_t)__builtin_ceilf(v0.y * 8388608.0f) << 9;
      T0.z = (uint32_t)__builtin_ceilf(v0.z * 8388608.0f) << 9;
      T0.w = (uint32_t)__builtin_ceilf(v0.w * 8388608.0f) << 9;
      T1.x = (uint32_t)__builtin_ceilf(v1.x * 8388608.0f) << 9;
      T1.y = (uint32_t)__builtin_ceilf(v1.y * 8388608.0f) << 9;
      T1.z = (uint32_t)__builtin_ceilf(v1.z * 8388608.0f) << 9;
      T1.w = (uint32_t)__builtin_ceilf(v1.w * 8388608.0f) << 9;
    }
    uint32_t* tp = thresh + (size_t)b * 800 + d0;
    *(uint4*)tp       = T0;
    *(uint4*)(tp + 4) = T1;
  }
}

// ---------------------------------------------------------------------------
// SG: fused spikegen + MFMA GEMM. grid 2560 x 256. Block bid: t = bid>>7,
// b0 = (bid&127)*64; flat row0 = bid*64 (== t*8192+b0).
// Phase 1: 1600 mask words -> LDS (each thread 6-7 words; 32 threefry/word,
//          cmp+addc accumulate). Phase 2 (after ONE barrier): r12 MFMA loop
//          with mask words read from LDS (stride 25 dwords -> conflict-free).
// 64-row tile: acc[2][4] (32 VGPR) + launch_bounds(256,8) -> 8 blocks/CU.
// ---------------------------------------------------------------------------
__global__ __launch_bounds__(256, 8) void spike_gemm(
    const uint32_t* __restrict__ thresh, const ushort_t* __restrict__ wp,
    const float* __restrict__ b1, float* __restrict__ cur1) {
  __shared__ uint32_t sM[64 * 25];    // 6.4 KB mask words [row][w]

  const int tid  = threadIdx.x;
  const int row0 = blockIdx.x << 6;   // flat row = t*8192 + b
  const int b0   = (blockIdx.x & 127) << 6;

  // ---- phase 1: spikegen into LDS ----
  for (int idx = tid; idx < 1600; idx += 256) {
    int r = idx / 25;                 // 0..63
    int w = idx - r * 25;             // 0..24
    int b = b0 + r;
    const uint32_t* tp = thresh + (size_t)b * 800 + (w << 5);
    uint32_t Ts[32];
#pragma unroll
    for (int q = 0; q < 8; ++q) {
      uint4 v = *(const uint4*)(tp + q * 4);
      Ts[q * 4 + 0] = v.x; Ts[q * 4 + 1] = v.y;
      Ts[q * 4 + 2] = v.z; Ts[q * 4 + 3] = v.w;
    }
    const uint32_t nw = (uint32_t)(row0 + r) * 784u + ((uint32_t)w << 5);
    uint32_t word = 0u;
#pragma unroll
    for (int j = 31; j >= 0; --j) {   // descending: bit for j lands at pos j
      uint32_t o0, o1;
      threefry_0_42(0u, nw + (uint32_t)j, o0, o1);
      uint32_t bits = o0 ^ o1;
      asm("v_cmp_lt_u32 vcc, %1, %2\n\t"
          "v_addc_co_u32 %0, vcc, %0, %0, vcc"
          : "+v"(word) : "v"(bits), "v"(Ts[j]) : "vcc");
    }
    sM[idx] = word;
  }
  __syncthreads();

  // ---- phase 2: MFMA GEMM (r12-verified structure/order; m-loop 4->2) ----
  const int wave = tid >> 6, lane = tid & 63;
  const int wr0  = (wave >> 1) << 5;
  const int wc0  = (wave & 1) << 6;
  const int lm   = lane & 15, quad = lane >> 4;
  const int qsh  = quad << 3;

  f32x4 acc[2][4];
#pragma unroll
  for (int m = 0; m < 2; ++m)
#pragma unroll
    for (int nn = 0; nn < 4; ++nn) acc[m][nn] = (f32x4){0.f, 0.f, 0.f, 0.f};

  const ushort_t* wbase = wp + (size_t)(wc0 + lm) * 800 + qsh;
  const uint32_t* mrow  = &sM[(wr0 + lm) * 25];

  for (int ko = 0; ko < 25; ++ko) {
    short8 a[2];
#pragma unroll
    for (int m = 0; m < 2; ++m) {
      uint32_t word = mrow[m * 400 + ko];          // LDS, stride 16*25 dwords
      uint32_t byte = (word >> qsh) & 0xffu;
      short8 av;
#pragma unroll
      for (int j = 0; j < 8; ++j)
        av[j] = (short)(((byte >> j) & 1u) ? 0x3F80 : 0);
      a[m] = av;
    }
    const int kof = ko << 5;
#pragma unroll
    for (int p = 0; p < 3; ++p) {
#pragma unroll
      for (int nn = 0; nn < 4; ++nn) {
        short8 bf = *(const short8*)&wbase[p * 102400 + nn * 16 * 800 + kof];
#pragma unroll
        for (int m = 0; m < 2; ++m)
          acc[m][nn] = __builtin_amdgcn_mfma_f32_16x16x32_bf16(
              a[m], bf, acc[m][nn], 0, 0, 0);
      }
    }
  }

  // epilogue: C/D layout col=lane&15, row=quad*4+reg (r10-verified)
#pragma unroll
  for (int nn = 0; nn < 4; ++nn) {
    int col = wc0 + nn * 16 + lm;
    float bias = b1[col];
#pragma unroll
    for (int m = 0; m < 2; ++m) {
#pragma unroll
      for (int r = 0; r < 4; ++r) {
        int grow = row0 + wr0 + m * 16 + quad * 4 + r;
        cur1[(size_t)grow * H_SZ + col] = acc[m][nn][r] + bias;
      }
    }
  }
}

// ---------------------------------------------------------------------------
// B1: LIF1, 16 lanes/row (byte-identical to r13-r16; absmax 0.0).
// ---------------------------------------------------------------------------
__global__ __launch_bounds__(256) void lif1_spikes(
    const float* __restrict__ cur1, uint32_t* __restrict__ masks) {
#pragma clang fp contract(off)
  const int g    = blockIdx.x * 256 + threadIdx.x;
  const int row  = g >> 4;
  const int s    = g & 15;
  const int lane = threadIdx.x & 63;

  float mem[8];
#pragma unroll
  for (int i = 0; i < 8; ++i) mem[i] = 0.0f;

  for (int t = 0; t < T_STEPS; ++t) {
    const float* base = cur1 + ((size_t)t * B_SZ + row) * H_SZ + s * 8;
    float4 c0 = *(const float4*)base;
    float4 c1 = *(const float4*)(base + 4);
    float cv[8] = {c0.x, c0.y, c0.z, c0.w, c1.x, c1.y, c1.z, c1.w};

    uint32_t bits8 = 0u;
#pragma unroll
    for (int q = 0; q < 8; ++q) {
      float m = mem[q];
      float reset = (m > 1.0f) ? 1.0f : 0.0f;
      m = 0.9f * m;
      m = m + cv[q];
      m = m - reset;
      mem[q] = m;
      bits8 |= (m > 1.0f) ? (1u << q) : 0u;
    }
    uint32_t part = bits8 << ((s & 3) * 8);
    part |= __shfl_xor(part, 1);
    part |= __shfl_xor(part, 2);
    uint32_t myw = __shfl(part, (lane & ~15) + 4 * (s & 3));
    if (s < 4)
      masks[((size_t)t * B_SZ + row) * 4 + s] = myw;
  }
}

// ---------------------------------------------------------------------------
// B2: layer-2 ascending-h add chain + LIF2 (byte-identical to r9-r16).
// ---------------------------------------------------------------------------
__global__ __launch_bounds__(320) void lif2_seq(
    const float* __restrict__ w2, const float* __restrict__ b2,
    const uint32_t* __restrict__ masks, float* __restrict__ out) {
#pragma clang fp contract(off)
  __shared__ __align__(16) float sW2[O_SZ][H_SZ];
  const int tid = threadIdx.x;
  for (int i = tid; i < O_SZ * H_SZ; i += 320)
    sW2[i >> 7][i & 127] = w2[i];
  __syncthreads();

  const int wave = tid >> 6;
  const int lane = tid & 63;
  const int row  = ((blockIdx.x >> 1) << 6) + lane;
  const int o    = (blockIdx.x & 1) * 5 + wave;
  const float bias = b2[o];

  float mem2 = 0.0f;
  int cnt = 0;
  const uint4* mbase = (const uint4*)masks;

  for (int t = 0; t < T_STEPS; ++t) {
    uint4 m = mbase[(size_t)t * B_SZ + row];
    uint32_t mw[4] = {m.x, m.y, m.z, m.w};
    float acc = 0.0f;
#pragma unroll
    for (int w = 0; w < 4; ++w) {
#pragma unroll
      for (int hc = 0; hc < 8; ++hc) {
        float4 wv = *(const float4*)&sW2[o][w * 32 + hc * 4];
        float vv[4] = {wv.x, wv.y, wv.z, wv.w};
#pragma unroll
        for (int bb = 0; bb < 4; ++bb) {
          float val = ((mw[w] >> (hc * 4 + bb)) & 1u) ? vv[bb] : 0.0f;
          acc = acc + val;
        }
      }
    }
    float c2 = acc + bias;
    float reset = (mem2 > 1.0f) ? 1.0f : 0.0f;
    mem2 = 0.9f * mem2;
    mem2 = mem2 + c2;
    mem2 = mem2 - reset;
    cnt += (mem2 > 1.0f) ? 1 : 0;
  }
  out[row * O_SZ + o] = (float)cnt / 20.0f;
}

extern "C" void kernel_launch(void* const* d_in, const int* in_sizes, int n_in,
                              void* d_out, int out_size, void* d_ws, size_t ws_size,
                              hipStream_t stream) {
  const float* x   = (const float*)d_in[0];  // [8192,784]
  const float* w1  = (const float*)d_in[1];  // [128,784]
  const float* b1  = (const float*)d_in[2];  // [128]
  const float* w2  = (const float*)d_in[3];  // [10,128]
  const float* b2  = (const float*)d_in[4];  // [10]
  float* out  = (float*)d_out;               // [8192,10]
  float*    cur1   = (float*)d_ws;
  uint32_t* masks  = (uint32_t*)((char*)d_ws + MASKS_OFF);
  ushort_t* wp     = (ushort_t*)((char*)d_ws + WP_OFF);
  uint32_t* thresh = (uint32_t*)((char*)d_ws + THR_OFF);

  prep       <<<dim3(3328), dim3(256), 0, stream>>>(w1, x, wp, thresh);
  spike_gemm <<<dim3(2560), dim3(256), 0, stream>>>(thresh, wp, b1, cur1);
  lif1_spikes<<<dim3(512),  dim3(256), 0, stream>>>(cur1, masks);
  lif2_seq   <<<dim3(256),  dim3(320), 0, stream>>>(w2, b2, masks, out);
}

// Round 3
// 424.667 us; speedup vs baseline: 1.0567x; 1.0567x over previous
//
#include <hip/hip_runtime.h>
#include <cstdint>

// SpikingCNN: B=8192, D=784, H=128, O=10, T=20, beta=0.9, thr=1.0
// R19: VALU-op reduction. Post-mortem of R17: occupancy 21->72% left dur
// UNCHANGED and VALU-busy TIME constant (284 vs 290 us) -> spike_gemm is
// VALU-THROUGHPUT-bound; R17's launch_bounds(256,8) also spilled Ts[32]
// (FETCH 42->80MB) and doubled wp/epilogue overhead. R19 reverts to the R16
// 128-row tile (grid 1280, acc[4][4], no min-waves cap) and cuts VALU ops:
//  (a) threefry add3 fusion: injection x0+=ks then round x0+=x1 rewritten as
//      x0 = x0 + ks + x1 -> v_add3_u32. u32 add is associative: bit-exact.
//      -4 ops/bit (73 -> 69).
//  (b) byte-LUT fragment expansion: sLUT[256] : byte -> short8 of bf16
//      {0,1.0}; phase-2 a-fragment = bfe + lshl + ds_read_b128 (~2 VALU +
//      1 LDS) instead of ~20 VALU of bit-select/pack. Same values -> same
//      MFMA inputs. Moves ~2000 ops/thread to the idle LDS pipe.
// RNG sequence, GEMM accumulation order (ko->p->mfma), C-layout unchanged
// (r9/r10/r12-verified). prep / lif1 / lif2 byte-identical (absmax 0.0).

#define T_STEPS 20
#define B_SZ   8192
#define D_SZ   784
#define H_SZ   128
#define O_SZ   10
#define CUR1_BYTES  83886080u                 // 20*8192*128*4
#define MASKS_OFF   83886080u                 // B1 masks: 655360 B
#define WP_OFF      84541440u                 // weight planes: 614400 B
#define THR_OFF     101539840u                // thresholds: 8192*800*4 = 26214400 B

typedef __attribute__((ext_vector_type(8))) short short8;
typedef __attribute__((ext_vector_type(4))) float f32x4;
typedef unsigned short ushort_t;

// rotl via v_alignbit_b32 (r15-verified: 1 instr/round).
#define ROTL_ASM(dst, src, sh)                                        \
  asm("v_alignbit_b32 %0, %1, %1, %2" : "=v"(dst) : "v"(src), "n"(32 - (sh)))

// JAX threefry2x32, key = (0, 42), counter = (0, c1). Injection adds fused
// with the following round's x0 += x1 as a 3-way add (v_add3_u32); u32
// wrapping addition is associative so the result is bit-identical.
__device__ __forceinline__ void threefry_0_42(uint32_t c1,
                                              uint32_t& o0, uint32_t& o1) {
  const uint32_t ks1 = 42u;
  const uint32_t ks2 = 42u ^ 0x1BD11BDAu;
  uint32_t x0, x1, r;
  x1 = c1 + ks1;                 // x0 = c0 + ks0 = 0
  // round 1: x0 = 0 + x1 -> copy
  x0 = x1;
  ROTL_ASM(r, x1, 13); x1 = r ^ x0;
#define TF_R(rot) { x0 += x1; ROTL_ASM(r, x1, rot); x1 = r ^ x0; }
  // C1 = x1 injection const; K0 = x0 injection const, fused via add3.
#define TF_IR(C1, K0, rot) { x1 += (C1); x0 = x0 + (K0) + x1; \
                             ROTL_ASM(r, x1, rot); x1 = r ^ x0; }
  TF_R(15) TF_R(26) TF_R(6)
  TF_IR(ks2 + 1u, ks1, 17) TF_R(29) TF_R(16) TF_R(24)
  TF_IR(2u,       ks2, 13) TF_R(15) TF_R(26) TF_R(6)
  TF_IR(ks1 + 3u, 0u,  17) TF_R(29) TF_R(16) TF_R(24)
  TF_IR(ks2 + 4u, ks1, 13) TF_R(15) TF_R(26) TF_R(6)
#undef TF_R
#undef TF_IR
  x0 += ks2; x1 += 5u;           // final injection (ks0+5 = 5)
  o0 = x0; o1 = x1;
}

__device__ __forceinline__ uint32_t rne_bf16_bits(float f) {
  uint32_t u = __float_as_uint(f);
  return (u + 0x7fffu + ((u >> 16) & 1u)) & 0xffff0000u;
}

// ---------------------------------------------------------------------------
// P: prep. Blocks 0..127: split w1 into 3 exact bf16 planes [128][800].
// Blocks 128..3327: pre-shifted thresholds thresh[b][d] = ceil(x*2^23)<<9,
// d in [784,800) padded 0 (never spikes; hits only zero weights).
// ---------------------------------------------------------------------------
__global__ __launch_bounds__(256) void prep(
    const float* __restrict__ w1, const float* __restrict__ x,
    ushort_t* __restrict__ wp, uint32_t* __restrict__ thresh) {
  if (blockIdx.x < 128) {
    const int h = blockIdx.x;
    for (int k = threadIdx.x; k < 800; k += 256) {
      float w = (k < D_SZ) ? w1[h * D_SZ + k] : 0.0f;
      uint32_t hb = rne_bf16_bits(w);
      float hi = __uint_as_float(hb);
      float r1 = w - hi;                      // exact
      uint32_t mb = rne_bf16_bits(r1);
      float mid = __uint_as_float(mb);
      float lo = r1 - mid;                    // exact
      uint32_t lb = __float_as_uint(lo);
      wp[0 * 102400 + h * 800 + k] = (ushort_t)(hb >> 16);
      wp[1 * 102400 + h * 800 + k] = (ushort_t)(mb >> 16);
      wp[2 * 102400 + h * 800 + k] = (ushort_t)(lb >> 16);
    }
  } else {
    const int gid = (blockIdx.x - 128) * 256 + threadIdx.x;  // 0..819199
    const int b = gid / 100;
    const int y = gid - b * 100;
    const int d0 = y << 3;
    uint4 T0 = {0u, 0u, 0u, 0u}, T1 = {0u, 0u, 0u, 0u};
    if (y < 98) {                                  // d0+7 <= 783
      const float* xr = x + (size_t)b * D_SZ + d0;
      float4 v0 = *(const float4*)xr;
      float4 v1 = *(const float4*)(xr + 4);
      T0.x = (uint32_t)__builtin_ceilf(v0.x * 8388608.0f) << 9;
      T0.y = (uint32_t)__builtin_ceilf(v0.y * 8388608.0f) << 9;
      T0.z = (uint32_t)__builtin_ceilf(v0.z * 8388608.0f) << 9;
      T0.w = (uint32_t)__builtin_ceilf(v0.w * 8388608.0f) << 9;
      T1.x = (uint32_t)__builtin_ceilf(v1.x * 8388608.0f) << 9;
      T1.y = (uint32_t)__builtin_ceilf(v1.y * 8388608.0f) << 9;
      T1.z = (uint32_t)__builtin_ceilf(v1.z * 8388608.0f) << 9;
      T1.w = (uint32_t)__builtin_ceilf(v1.w * 8388608.0f) << 9;
    }
    uint32_t* tp = thresh + (size_t)b * 800 + d0;
    *(uint4*)tp       = T0;
    *(uint4*)(tp + 4) = T1;
  }
}

// ---------------------------------------------------------------------------
// SG: fused spikegen + MFMA GEMM. grid 1280 x 256. Block bid: t = bid>>6,
// b0 = (bid&63)*128; flat row0 = bid*128 (== t*8192+b0).
// Phase 1: 3200 mask words -> LDS; LUT init (256 x short8 bf16 expansion).
// Phase 2 (after ONE barrier): r12 MFMA loop; a-fragments via LUT b128 read.
// ---------------------------------------------------------------------------
__global__ __launch_bounds__(256) void spike_gemm(
    const uint32_t* __restrict__ thresh, const ushort_t* __restrict__ wp,
    const float* __restrict__ b1, float* __restrict__ cur1) {
  __shared__ uint32_t sM[128 * 25];                 // 12.8 KB mask words [row][w]
  __shared__ __align__(16) uint32_t sLUT[256][4];   // 4 KB byte -> short8 bf16

  const int tid  = threadIdx.x;
  const int row0 = blockIdx.x << 7;   // flat row = t*8192 + b
  const int b0   = (blockIdx.x & 63) << 7;

  // ---- LUT init: entry tid = bf16 {0,1} expansion of byte tid ----
  {
    uint32_t v = (uint32_t)tid;
    sLUT[v][0] = ((v &   1u) ? 0x3F80u : 0u) | ((v &   2u) ? 0x3F800000u : 0u);
    sLUT[v][1] = ((v &   4u) ? 0x3F80u : 0u) | ((v &   8u) ? 0x3F800000u : 0u);
    sLUT[v][2] = ((v &  16u) ? 0x3F80u : 0u) | ((v &  32u) ? 0x3F800000u : 0u);
    sLUT[v][3] = ((v &  64u) ? 0x3F80u : 0u) | ((v & 128u) ? 0x3F800000u : 0u);
  }

  // ---- phase 1: spikegen into LDS ----
  for (int idx = tid; idx < 3200; idx += 256) {
    int r = idx / 25;                 // 0..127
    int w = idx - r * 25;             // 0..24
    int b = b0 + r;
    const uint32_t* tp = thresh + (size_t)b * 800 + (w << 5);
    uint32_t Ts[32];
#pragma unroll
    for (int q = 0; q < 8; ++q) {
      uint4 v = *(const uint4*)(tp + q * 4);
      Ts[q * 4 + 0] = v.x; Ts[q * 4 + 1] = v.y;
      Ts[q * 4 + 2] = v.z; Ts[q * 4 + 3] = v.w;
    }
    const uint32_t nw = (uint32_t)(row0 + r) * 784u + ((uint32_t)w << 5);
    uint32_t word = 0u;
#pragma unroll
    for (int j = 31; j >= 0; --j) {   // descending: bit for j lands at pos j
      uint32_t o0, o1;
      threefry_0_42(nw + (uint32_t)j, o0, o1);
      uint32_t bits = o0 ^ o1;
      asm("v_cmp_lt_u32 vcc, %1, %2\n\t"
          "v_addc_co_u32 %0, vcc, %0, %0, vcc"
          : "+v"(word) : "v"(bits), "v"(Ts[j]) : "vcc");
    }
    sM[idx] = word;
  }
  __syncthreads();

  // ---- phase 2: MFMA GEMM (r12-verified structure/order) ----
  const int wave = tid >> 6, lane = tid & 63;
  const int wr0  = (wave >> 1) << 6;
  const int wc0  = (wave & 1) << 6;
  const int lm   = lane & 15, quad = lane >> 4;
  const int qsh  = quad << 3;

  f32x4 acc[4][4];
#pragma unroll
  for (int m = 0; m < 4; ++m)
#pragma unroll
    for (int nn = 0; nn < 4; ++nn) acc[m][nn] = (f32x4){0.f, 0.f, 0.f, 0.f};

  const ushort_t* wbase = wp + (size_t)(wc0 + lm) * 800 + qsh;
  const uint32_t* mrow  = &sM[(wr0 + lm) * 25];

  for (int ko = 0; ko < 25; ++ko) {
    short8 a[4];
#pragma unroll
    for (int m = 0; m < 4; ++m) {
      uint32_t word = mrow[m * 400 + ko];          // LDS, stride 16*25 dwords
      uint32_t byte = (word >> qsh) & 0xffu;       // v_bfe
      a[m] = *(const short8*)&sLUT[byte][0];       // ds_read_b128 gather
    }
    const int kof = ko << 5;
#pragma unroll
    for (int p = 0; p < 3; ++p) {
#pragma unroll
      for (int nn = 0; nn < 4; ++nn) {
        short8 bf = *(const short8*)&wbase[p * 102400 + nn * 16 * 800 + kof];
#pragma unroll
        for (int m = 0; m < 4; ++m)
          acc[m][nn] = __builtin_amdgcn_mfma_f32_16x16x32_bf16(
              a[m], bf, acc[m][nn], 0, 0, 0);
      }
    }
  }

  // epilogue: C/D layout col=lane&15, row=quad*4+reg (r10-verified)
#pragma unroll
  for (int nn = 0; nn < 4; ++nn) {
    int col = wc0 + nn * 16 + lm;
    float bias = b1[col];
#pragma unroll
    for (int m = 0; m < 4; ++m) {
#pragma unroll
      for (int r = 0; r < 4; ++r) {
        int grow = row0 + wr0 + m * 16 + quad * 4 + r;
        cur1[(size_t)grow * H_SZ + col] = acc[m][nn][r] + bias;
      }
    }
  }
}

// ---------------------------------------------------------------------------
// B1: LIF1, 16 lanes/row (byte-identical to r13-r16; absmax 0.0).
// ---------------------------------------------------------------------------
__global__ __launch_bounds__(256) void lif1_spikes(
    const float* __restrict__ cur1, uint32_t* __restrict__ masks) {
#pragma clang fp contract(off)
  const int g    = blockIdx.x * 256 + threadIdx.x;
  const int row  = g >> 4;
  const int s    = g & 15;
  const int lane = threadIdx.x & 63;

  float mem[8];
#pragma unroll
  for (int i = 0; i < 8; ++i) mem[i] = 0.0f;

  for (int t = 0; t < T_STEPS; ++t) {
    const float* base = cur1 + ((size_t)t * B_SZ + row) * H_SZ + s * 8;
    float4 c0 = *(const float4*)base;
    float4 c1 = *(const float4*)(base + 4);
    float cv[8] = {c0.x, c0.y, c0.z, c0.w, c1.x, c1.y, c1.z, c1.w};

    uint32_t bits8 = 0u;
#pragma unroll
    for (int q = 0; q < 8; ++q) {
      float m = mem[q];
      float reset = (m > 1.0f) ? 1.0f : 0.0f;
      m = 0.9f * m;
      m = m + cv[q];
      m = m - reset;
      mem[q] = m;
      bits8 |= (m > 1.0f) ? (1u << q) : 0u;
    }
    uint32_t part = bits8 << ((s & 3) * 8);
    part |= __shfl_xor(part, 1);
    part |= __shfl_xor(part, 2);
    uint32_t myw = __shfl(part, (lane & ~15) + 4 * (s & 3));
    if (s < 4)
      masks[((size_t)t * B_SZ + row) * 4 + s] = myw;
  }
}

// ---------------------------------------------------------------------------
// B2: layer-2 ascending-h add chain + LIF2 (byte-identical to r9-r16).
// ---------------------------------------------------------------------------
__global__ __launch_bounds__(320) void lif2_seq(
    const float* __restrict__ w2, const float* __restrict__ b2,
    const uint32_t* __restrict__ masks, float* __restrict__ out) {
#pragma clang fp contract(off)
  __shared__ __align__(16) float sW2[O_SZ][H_SZ];
  const int tid = threadIdx.x;
  for (int i = tid; i < O_SZ * H_SZ; i += 320)
    sW2[i >> 7][i & 127] = w2[i];
  __syncthreads();

  const int wave = tid >> 6;
  const int lane = tid & 63;
  const int row  = ((blockIdx.x >> 1) << 6) + lane;
  const int o    = (blockIdx.x & 1) * 5 + wave;
  const float bias = b2[o];

  float mem2 = 0.0f;
  int cnt = 0;
  const uint4* mbase = (const uint4*)masks;

  for (int t = 0; t < T_STEPS; ++t) {
    uint4 m = mbase[(size_t)t * B_SZ + row];
    uint32_t mw[4] = {m.x, m.y, m.z, m.w};
    float acc = 0.0f;
#pragma unroll
    for (int w = 0; w < 4; ++w) {
#pragma unroll
      for (int hc = 0; hc < 8; ++hc) {
        float4 wv = *(const float4*)&sW2[o][w * 32 + hc * 4];
        float vv[4] = {wv.x, wv.y, wv.z, wv.w};
#pragma unroll
        for (int bb = 0; bb < 4; ++bb) {
          float val = ((mw[w] >> (hc * 4 + bb)) & 1u) ? vv[bb] : 0.0f;
          acc = acc + val;
        }
      }
    }
    float c2 = acc + bias;
    float reset = (mem2 > 1.0f) ? 1.0f : 0.0f;
    mem2 = 0.9f * mem2;
    mem2 = mem2 + c2;
    mem2 = mem2 - reset;
    cnt += (mem2 > 1.0f) ? 1 : 0;
  }
  out[row * O_SZ + o] = (float)cnt / 20.0f;
}

extern "C" void kernel_launch(void* const* d_in, const int* in_sizes, int n_in,
                              void* d_out, int out_size, void* d_ws, size_t ws_size,
                              hipStream_t stream) {
  const float* x   = (const float*)d_in[0];  // [8192,784]
  const float* w1  = (const float*)d_in[1];  // [128,784]
  const float* b1  = (const float*)d_in[2];  // [128]
  const float* w2  = (const float*)d_in[3];  // [10,128]
  const float* b2  = (const float*)d_in[4];  // [10]
  float* out  = (float*)d_out;               // [8192,10]
  float*    cur1   = (float*)d_ws;
  uint32_t* masks  = (uint32_t*)((char*)d_ws + MASKS_OFF);
  ushort_t* wp     = (ushort_t*)((char*)d_ws + WP_OFF);
  uint32_t* thresh = (uint32_t*)((char*)d_ws + THR_OFF);

  prep       <<<dim3(3328), dim3(256), 0, stream>>>(w1, x, wp, thresh);
  spike_gemm <<<dim3(1280), dim3(256), 0, stream>>>(thresh, wp, b1, cur1);
  lif1_spikes<<<dim3(512),  dim3(256), 0, stream>>>(cur1, masks);
  lif2_seq   <<<dim3(256),  dim3(320), 0, stream>>>(w2, b2, masks, out);
}

// Round 6
// 399.715 us; speedup vs baseline: 1.1227x; 1.0624x over previous
//
#include <hip/hip_runtime.h>
#include <cstdint>

// SpikingCNN: B=8192, D=784, H=128, O=10, T=20, beta=0.9, thr=1.0
// R22 = R21 with the WORKSPACE ALIASING fix. R21's absmax 0.2 root cause:
// masks needs 20*8192*4 WORDS = 2,621,440 B, but WP_OFF-MASKS_OFF was only
// 655,360 B (old comment confused words/bytes) -> mask writes for t=5..9
// landed inside the wp weight planes. Harmless in the old 4-kernel pipeline
// (lif1 ran after spike_gemm finished with wp) but FATAL in the fused kernel
// (group 1 writes masks while groups 2-3 still read wp -> corrupt B-frags
// for t>=10). Fix: masks moved to offset 0 (old cur1 region, now unused).
// R20/R21 rationale: R17 (occupancy null) + R19 (op cuts) established
// spike_gemm is VALU-throughput-bound at ~260us of threefry; remaining
// targets were the 160MB cur1 round-trip + lif1 kernel + launch gap.
// spike_lif1: block owns 16 batch rows for ALL 20 t (grid 512 = 2
// blocks/CU). Per 5-t group: phase1 spikegen 2000 words -> double-buffered
// LDS (500/wave); ONE barrier; phase2 GEMM with B-fragments amortized over
// 5 t (acc[5][2]); LIF1 in accumulator registers + ballot spike packing
// (wave w owns mask word w). cur1 never materialized; lif1_spikes deleted.
// Exactness:
//  - RNG: nw = (t*8192+b)*784+32w, bits=o0^o1 of threefry((0,42),(0,n))
//    (r9-verified), cmp+addc accumulate, j descending.
//  - GEMM per-element accumulation order ko->p unchanged (r12-verified);
//    C/D layout col=lane&15, row=quad*4+reg (r10-verified).
//  - LIF1 op order reset/(0.9*m)/+cv/-reset with contract(off), cv=acc+bias
//    (identical f32 value to the old cur1 store/load round-trip).
//  - masks bit h=32w+16nn+lm identical to lif1_spikes output (re-derived).
// prep / lif2 byte-identical (absmax 0.0).

#define T_STEPS 20
#define B_SZ   8192
#define D_SZ   784
#define H_SZ   128
#define O_SZ   10
#define MASKS_OFF   0u                        // masks: 2,621,440 B (old cur1 area)
#define WP_OFF      84541440u                 // weight planes: 614,400 B
#define THR_OFF     101539840u                // thresholds: 8192*800*4 = 26,214,400 B

typedef __attribute__((ext_vector_type(8))) short short8;
typedef __attribute__((ext_vector_type(4))) float f32x4;
typedef unsigned short ushort_t;

// rotl via v_alignbit_b32 (r15-verified: 1 instr/round).
#define ROTL_ASM(dst, src, sh)                                        \
  asm("v_alignbit_b32 %0, %1, %1, %2" : "=v"(dst) : "v"(src), "n"(32 - (sh)))

// JAX threefry2x32, key = (0, 42), counter = (0, c1). Injection adds fused
// via v_add3_u32 (associative u32 adds: bit-exact; R19-verified).
__device__ __forceinline__ void threefry_0_42(uint32_t c1,
                                              uint32_t& o0, uint32_t& o1) {
  const uint32_t ks1 = 42u;
  const uint32_t ks2 = 42u ^ 0x1BD11BDAu;
  uint32_t x0, x1, r;
  x1 = c1 + ks1;                 // x0 = c0 + ks0 = 0
  x0 = x1;                       // round 1: x0 = 0 + x1
  ROTL_ASM(r, x1, 13); x1 = r ^ x0;
#define TF_R(rot) { x0 += x1; ROTL_ASM(r, x1, rot); x1 = r ^ x0; }
#define TF_IR(C1, K0, rot) { x1 += (C1); x0 = x0 + (K0) + x1; \
                             ROTL_ASM(r, x1, rot); x1 = r ^ x0; }
  TF_R(15) TF_R(26) TF_R(6)
  TF_IR(ks2 + 1u, ks1, 17) TF_R(29) TF_R(16) TF_R(24)
  TF_IR(2u,       ks2, 13) TF_R(15) TF_R(26) TF_R(6)
  TF_IR(ks1 + 3u, 0u,  17) TF_R(29) TF_R(16) TF_R(24)
  TF_IR(ks2 + 4u, ks1, 13) TF_R(15) TF_R(26) TF_R(6)
#undef TF_R
#undef TF_IR
  x0 += ks2; x1 += 5u;           // final injection (ks0+5 = 5)
  o0 = x0; o1 = x1;
}

__device__ __forceinline__ uint32_t rne_bf16_bits(float f) {
  uint32_t u = __float_as_uint(f);
  return (u + 0x7fffu + ((u >> 16) & 1u)) & 0xffff0000u;
}

// ---------------------------------------------------------------------------
// P: prep. Blocks 0..127: split w1 into 3 exact bf16 planes [128][800].
// Blocks 128..3327: pre-shifted thresholds thresh[b][d] = ceil(x*2^23)<<9,
// d in [784,800) padded 0 (never spikes; hits only zero weights).
// ---------------------------------------------------------------------------
__global__ __launch_bounds__(256) void prep(
    const float* __restrict__ w1, const float* __restrict__ x,
    ushort_t* __restrict__ wp, uint32_t* __restrict__ thresh) {
  if (blockIdx.x < 128) {
    const int h = blockIdx.x;
    for (int k = threadIdx.x; k < 800; k += 256) {
      float w = (k < D_SZ) ? w1[h * D_SZ + k] : 0.0f;
      uint32_t hb = rne_bf16_bits(w);
      float hi = __uint_as_float(hb);
      float r1 = w - hi;                      // exact
      uint32_t mb = rne_bf16_bits(r1);
      float mid = __uint_as_float(mb);
      float lo = r1 - mid;                    // exact
      uint32_t lb = __float_as_uint(lo);
      wp[0 * 102400 + h * 800 + k] = (ushort_t)(hb >> 16);
      wp[1 * 102400 + h * 800 + k] = (ushort_t)(mb >> 16);
      wp[2 * 102400 + h * 800 + k] = (ushort_t)(lb >> 16);
    }
  } else {
    const int gid = (blockIdx.x - 128) * 256 + threadIdx.x;  // 0..819199
    const int b = gid / 100;
    const int y = gid - b * 100;
    const int d0 = y << 3;
    uint4 T0 = {0u, 0u, 0u, 0u}, T1 = {0u, 0u, 0u, 0u};
    if (y < 98) {                                  // d0+7 <= 783
      const float* xr = x + (size_t)b * D_SZ + d0;
      float4 v0 = *(const float4*)xr;
      float4 v1 = *(const float4*)(xr + 4);
      T0.x = (uint32_t)__builtin_ceilf(v0.x * 8388608.0f) << 9;
      T0.y = (uint32_t)__builtin_ceilf(v0.y * 8388608.0f) << 9;
      T0.z = (uint32_t)__builtin_ceilf(v0.z * 8388608.0f) << 9;
      T0.w = (uint32_t)__builtin_ceilf(v0.w * 8388608.0f) << 9;
      T1.x = (uint32_t)__builtin_ceilf(v1.x * 8388608.0f) << 9;
      T1.y = (uint32_t)__builtin_ceilf(v1.y * 8388608.0f) << 9;
      T1.z = (uint32_t)__builtin_ceilf(v1.z * 8388608.0f) << 9;
      T1.w = (uint32_t)__builtin_ceilf(v1.w * 8388608.0f) << 9;
    }
    uint32_t* tp = thresh + (size_t)b * 800 + d0;
    *(uint4*)tp       = T0;
    *(uint4*)(tp + 4) = T1;
  }
}

// ---------------------------------------------------------------------------
// F: fused spikegen + GEMM + LIF1. grid 512 x 256 (2 blocks/CU). Block owns
// batch rows [bid*16, bid*16+16) for ALL t. 4 groups of 5 t, double-buffered
// sM, ONE barrier per group. Wave w owns cols [32w, 32w+32) = mask word w.
// ---------------------------------------------------------------------------
__global__ __launch_bounds__(256) void spike_lif1(
    const uint32_t* __restrict__ thresh, const ushort_t* __restrict__ wp,
    const float* __restrict__ b1, uint32_t* __restrict__ masks) {
#pragma clang fp contract(off)
  __shared__ uint32_t sM[2][5][16][25];             // 16 KB mask words
  __shared__ __align__(16) uint32_t sLUT[256][4];   // 4 KB byte -> short8 bf16

  const int tid    = threadIdx.x;
  const int bid    = blockIdx.x;
  const int b_row0 = bid << 4;        // batch rows [b_row0, b_row0+16)

  // ---- LUT init: entry tid = bf16 {0,1} expansion of byte tid ----
  {
    uint32_t v = (uint32_t)tid;
    sLUT[v][0] = ((v &   1u) ? 0x3F80u : 0u) | ((v &   2u) ? 0x3F800000u : 0u);
    sLUT[v][1] = ((v &   4u) ? 0x3F80u : 0u) | ((v &   8u) ? 0x3F800000u : 0u);
    sLUT[v][2] = ((v &  16u) ? 0x3F80u : 0u) | ((v &  32u) ? 0x3F800000u : 0u);
    sLUT[v][3] = ((v &  64u) ? 0x3F80u : 0u) | ((v & 128u) ? 0x3F800000u : 0u);
  }

  const int wave = tid >> 6, lane = tid & 63;
  const int lm   = lane & 15, quad = lane >> 4;
  const int qsh  = quad << 3;

  const ushort_t* wbase = wp + (size_t)(wave * 32 + lm) * 800 + qsh;
  const float bias0 = b1[wave * 32 + lm];
  const float bias1 = b1[wave * 32 + 16 + lm];

  f32x4 mem0 = {0.f, 0.f, 0.f, 0.f};   // rows quad*4+rl, cols 32w+lm
  f32x4 mem1 = {0.f, 0.f, 0.f, 0.f};   // rows quad*4+rl, cols 32w+16+lm

  for (int g = 0; g < 4; ++g) {
    const int t0  = 5 * g;
    const int buf = g & 1;

    // ---- phase 1: spikegen, wave range [500*wave, 500*wave+500) ----
    const int base = 500 * wave;
    for (int it = 0; it < 8; ++it) {
      if (it < 7 || lane < 52) {        // 500 = 7*64 + 52
        int widx = base + it * 64 + lane;
        int tt  = widx / 400;           // 0..4
        int rem = widx - tt * 400;
        int r   = rem / 25;             // 0..15
        int w   = rem - r * 25;         // 0..24
        const uint32_t* tp = thresh + (size_t)(b_row0 + r) * 800 + (w << 5);
        uint32_t Ts[32];
#pragma unroll
        for (int q = 0; q < 8; ++q) {
          uint4 v = *(const uint4*)(tp + q * 4);
          Ts[q * 4 + 0] = v.x; Ts[q * 4 + 1] = v.y;
          Ts[q * 4 + 2] = v.z; Ts[q * 4 + 3] = v.w;
        }
        const uint32_t nw =
            ((uint32_t)(t0 + tt) * 8192u + (uint32_t)(b_row0 + r)) * 784u +
            ((uint32_t)w << 5);
        uint32_t word = 0u;
#pragma unroll
        for (int j = 31; j >= 0; --j) { // descending: bit j lands at pos j
          uint32_t o0, o1;
          threefry_0_42(nw + (uint32_t)j, o0, o1);
          uint32_t bits = o0 ^ o1;
          asm("v_cmp_lt_u32 vcc, %1, %2\n\t"
              "v_addc_co_u32 %0, vcc, %0, %0, vcc"
              : "+v"(word) : "v"(bits), "v"(Ts[j]) : "vcc");
        }
        sM[buf][tt][r][w] = word;
      }
    }
    __syncthreads();

    // ---- phase 2: GEMM for 5 t with shared B-fragments ----
    f32x4 acc[5][2];
#pragma unroll
    for (int tt = 0; tt < 5; ++tt) {
      acc[tt][0] = (f32x4){0.f, 0.f, 0.f, 0.f};
      acc[tt][1] = (f32x4){0.f, 0.f, 0.f, 0.f};
    }
    for (int ko = 0; ko < 25; ++ko) {
      short8 a[5];
#pragma unroll
      for (int tt = 0; tt < 5; ++tt) {
        uint32_t word = sM[buf][tt][lm][ko];
        a[tt] = *(const short8*)&sLUT[(word >> qsh) & 0xffu][0];
      }
      const int kof = ko << 5;
#pragma unroll
      for (int p = 0; p < 3; ++p) {
#pragma unroll
        for (int nn = 0; nn < 2; ++nn) {
          short8 bf = *(const short8*)&wbase[p * 102400 + nn * 12800 + kof];
#pragma unroll
          for (int tt = 0; tt < 5; ++tt)
            acc[tt][nn] = __builtin_amdgcn_mfma_f32_16x16x32_bf16(
                a[tt], bf, acc[tt][nn], 0, 0, 0);
        }
      }
    }

    // ---- LIF1 update in registers + ballot pack (t ascending) ----
#pragma unroll
    for (int tt = 0; tt < 5; ++tt) {
      const int t = t0 + tt;
      unsigned long long bk0[4], bk1[4];
#pragma unroll
      for (int rl = 0; rl < 4; ++rl) {
        float cv0 = acc[tt][0][rl] + bias0;   // == old cur1 store/load value
        float m0  = mem0[rl];
        float r0  = (m0 > 1.0f) ? 1.0f : 0.0f;
        m0 = 0.9f * m0;
        m0 = m0 + cv0;
        m0 = m0 - r0;
        mem0[rl] = m0;
        float cv1 = acc[tt][1][rl] + bias1;
        float m1  = mem1[rl];
        float r1  = (m1 > 1.0f) ? 1.0f : 0.0f;
        m1 = 0.9f * m1;
        m1 = m1 + cv1;
        m1 = m1 - r1;
        mem1[rl] = m1;
        // ballot bit(lane=16q+lm) = spike(row=4q+rl, col 32w+16nn+lm)
        bk0[rl] = __ballot(m0 > 1.0f);
        bk1[rl] = __ballot(m1 > 1.0f);
      }
      // row = lane (<16) = 4q+rl -> q=lane>>2, rl=lane&3; word w of that row:
      // bits 15..0 = k0[rl]>>(16q), bits 31..16 = k1[rl]>>(16q).
      if (lane < 16) {
        const int q  = lane >> 2;
        const int rl = lane & 3;
        unsigned long long s0 =
            (rl & 2) ? ((rl & 1) ? bk0[3] : bk0[2])
                     : ((rl & 1) ? bk0[1] : bk0[0]);
        unsigned long long s1 =
            (rl & 2) ? ((rl & 1) ? bk1[3] : bk1[2])
                     : ((rl & 1) ? bk1[1] : bk1[0]);
        uint32_t wd = ((uint32_t)(s0 >> (16 * q)) & 0xffffu) |
                      (((uint32_t)(s1 >> (16 * q)) & 0xffffu) << 16);
        masks[((size_t)t * B_SZ + b_row0 + lane) * 4 + wave] = wd;
      }
    }
  }
}

// ---------------------------------------------------------------------------
// B2: layer-2 ascending-h add chain + LIF2 (byte-identical to r9-r19).
// ---------------------------------------------------------------------------
__global__ __launch_bounds__(320) void lif2_seq(
    const float* __restrict__ w2, const float* __restrict__ b2,
    const uint32_t* __restrict__ masks, float* __restrict__ out) {
#pragma clang fp contract(off)
  __shared__ __align__(16) float sW2[O_SZ][H_SZ];
  const int tid = threadIdx.x;
  for (int i = tid; i < O_SZ * H_SZ; i += 320)
    sW2[i >> 7][i & 127] = w2[i];
  __syncthreads();

  const int wave = tid >> 6;
  const int lane = tid & 63;
  const int row  = ((blockIdx.x >> 1) << 6) + lane;
  const int o    = (blockIdx.x & 1) * 5 + wave;
  const float bias = b2[o];

  float mem2 = 0.0f;
  int cnt = 0;
  const uint4* mbase = (const uint4*)masks;

  for (int t = 0; t < T_STEPS; ++t) {
    uint4 m = mbase[(size_t)t * B_SZ + row];
    uint32_t mw[4] = {m.x, m.y, m.z, m.w};
    float acc = 0.0f;
#pragma unroll
    for (int w = 0; w < 4; ++w) {
#pragma unroll
      for (int hc = 0; hc < 8; ++hc) {
        float4 wv = *(const float4*)&sW2[o][w * 32 + hc * 4];
        float vv[4] = {wv.x, wv.y, wv.z, wv.w};
#pragma unroll
        for (int bb = 0; bb < 4; ++bb) {
          float val = ((mw[w] >> (hc * 4 + bb)) & 1u) ? vv[bb] : 0.0f;
          acc = acc + val;
        }
      }
    }
    float c2 = acc + bias;
    float reset = (mem2 > 1.0f) ? 1.0f : 0.0f;
    mem2 = 0.9f * mem2;
    mem2 = mem2 + c2;
    mem2 = mem2 - reset;
    cnt += (mem2 > 1.0f) ? 1 : 0;
  }
  out[row * O_SZ + o] = (float)cnt / 20.0f;
}

extern "C" void kernel_launch(void* const* d_in, const int* in_sizes, int n_in,
                              void* d_out, int out_size, void* d_ws, size_t ws_size,
                              hipStream_t stream) {
  const float* x   = (const float*)d_in[0];  // [8192,784]
  const float* w1  = (const float*)d_in[1];  // [128,784]
  const float* b1  = (const float*)d_in[2];  // [128]
  const float* w2  = (const float*)d_in[3];  // [10,128]
  const float* b2  = (const float*)d_in[4];  // [10]
  float* out  = (float*)d_out;               // [8192,10]
  uint32_t* masks  = (uint32_t*)((char*)d_ws + MASKS_OFF);
  ushort_t* wp     = (ushort_t*)((char*)d_ws + WP_OFF);
  uint32_t* thresh = (uint32_t*)((char*)d_ws + THR_OFF);

  prep      <<<dim3(3328), dim3(256), 0, stream>>>(w1, x, wp, thresh);
  spike_lif1<<<dim3(512),  dim3(256), 0, stream>>>(thresh, wp, b1, masks);
  lif2_seq  <<<dim3(256),  dim3(320), 0, stream>>>(w2, b2, masks, out);
}